// Round 1
// 351.899 us; speedup vs baseline: 1.1761x; 1.1761x over previous
//
#include <hip/hip_runtime.h>

// Problem: B=32, CI=64, CO=64, H=128, W=128, E=5, T=10, 5x5 SAME conv (MoDE).
// d_out = y[32*64*128*128] f32 ++ task_id[32] (as float).
//
// ws layout:
//   xt : [32 b][132 hp][8 cc][132 wp][8 ci] bf16 = 71,368,704 B
//        hp = h+2 (rows 0,1,130,131 zero), wp = w+2 (borders zero)
//   wk : [10 t][25 tap][64 co][64 ci] bf16       =  2,048,000 B
// requires ws_size >= 73,416,704 bytes.
#define WK_OFFSET_BYTES 71368704ull

using bf16x8   = __attribute__((ext_vector_type(8)))  __bf16;
using floatx16 = __attribute__((ext_vector_type(16))) float;

static __device__ __forceinline__ unsigned short f2bf(float f) {
    unsigned int u = __float_as_uint(f);
    u += 0x7FFFu + ((u >> 16) & 1u);          // round-to-nearest-even (finite inputs)
    return (unsigned short)(u >> 16);
}

static __device__ __forceinline__ floatx16 mfma16(bf16x8 a, bf16x8 b, floatx16 c) {
    return __builtin_amdgcn_mfma_f32_32x32x16_bf16(a, b, c, 0, 0, 0);
}

// async global->LDS DMA, 16B per lane. LDS dest = wave-uniform base + lane*16
// (our per-lane lds pointers are consecutive, so first-lane base is correct).
static __device__ __forceinline__ void gload_lds16(const void* g, void* l) {
    __builtin_amdgcn_global_load_lds(
        (const __attribute__((address_space(1))) void*)g,
        (__attribute__((address_space(3))) void*)l, 16, 0, 0);
}

// ---------------------------------------------------------------------------
// Kernel 1 (fused): blocks 0..4223  = transform x -> xt (32 b x 132 padded rows)
//                   blocks 4224..4383 = gate softmax + per-task kernel synthesis
// ---------------------------------------------------------------------------
__global__ __launch_bounds__(256) void pre_kernel(
    const float* __restrict__ x,
    const float* __restrict__ gate_w, const float* __restrict__ gate_b,
    const float* __restrict__ w5, const float* __restrict__ w3,
    const float* __restrict__ w1, const float* __restrict__ wavg3,
    const float* __restrict__ wavg5, const int* __restrict__ task_id,
    unsigned short* __restrict__ xt, unsigned short* __restrict__ wk,
    float* __restrict__ out_task)
{
    const int blk = blockIdx.x;
    const int tid = threadIdx.x;
    __shared__ float g[5][64];

    if (blk < 4224) {
        // -------- transform: one padded row (b, hp) per block --------
        const int b  = blk / 132;
        const int hp = blk - b * 132;
        const int h  = hp - 2;
        const bool vrow = (h >= 0) && (h < 128);
        unsigned short* dst_row = xt + (size_t)blk * 8448;

        for (int i = tid; i < 1056; i += 256) {      // 8 cc * 132 wp uint4 blocks
            int cc = i / 132;
            int wp = i - cc * 132;
            unsigned int pk[4] = {0u, 0u, 0u, 0u};
            if (vrow && wp >= 2 && wp < 130) {
                const float* xp = x + (((size_t)(b * 64 + cc * 8) * 128 + h) * 128 + (wp - 2));
                #pragma unroll
                for (int j = 0; j < 4; ++j) {
                    unsigned short lo = f2bf(xp[(2 * j)     * 16384]);
                    unsigned short hi = f2bf(xp[(2 * j + 1) * 16384]);
                    pk[j] = (unsigned int)lo | ((unsigned int)hi << 16);
                }
            }
            *(uint4*)(dst_row + (size_t)i * 8) = make_uint4(pk[0], pk[1], pk[2], pk[3]);
        }
    } else {
        // -------- prep: per-task 5x5 kernel synthesis --------
        const int pb = blk - 4224;
        const int t = pb >> 4;          // 0..9
        const int chunk = pb & 15;      // 0..15

        if (tid < 64) {
            float l[5];
            float m = -1e30f;
            #pragma unroll
            for (int e = 0; e < 5; ++e) {
                l[e] = gate_w[(e * 64 + tid) * 10 + t] + gate_b[e * 64 + tid];
                m = fmaxf(m, l[e]);
            }
            float s = 0.f;
            #pragma unroll
            for (int e = 0; e < 5; ++e) { l[e] = expf(l[e] - m); s += l[e]; }
            float inv = 1.f / s;
            #pragma unroll
            for (int e = 0; e < 5; ++e) g[e][tid] = l[e] * inv;
        }
        __syncthreads();

        for (int it = 0; it < 25; ++it) {
            int idx = chunk * 6400 + it * 256 + tid;
            int ci  = idx & 63;
            int o   = (idx >> 6) & 63;
            int tap = idx >> 12;               // 0..24
            int ky = tap / 5, kx = tap - ky * 5;

            float v = g[0][o] * w5[(o * 64 + ci) * 25 + tap];
            bool in3 = (ky >= 1 && ky <= 3 && kx >= 1 && kx <= 3);
            if (in3) {
                v += g[1][o] * w3[(o * 64 + ci) * 9 + (ky - 1) * 3 + (kx - 1)];
                v += g[3][o] * wavg3[o * 64 + ci] * (1.f / 9.f);
            }
            if (ky == 2 && kx == 2) v += g[2][o] * w1[o * 64 + ci];
            v += g[4][o] * wavg5[o * 64 + ci] * (1.f / 25.f);

            wk[(t * 25 + tap) * 4096 + o * 64 + ci] = f2bf(v);
        }

        if (pb == 0 && tid < 32) out_task[tid] = (float)task_id[tid];
    }
}

// ---------------------------------------------------------------------------
// Kernel 2: MFMA conv, pipelined.
// Block = 512 thr (8 waves), tile = 64co x (8 rows x 128 w); wave = 1 row.
// q = 16-ci quarter of K. Per q:
//   input:  12 rows x [2 cc][132 wp][8 ci] = 50,688 B (double-buffered, DMA)
//   weights:[25 tap][2 cih][64 co][8 ci]  = 51,200 B (single-buffered, DMA)
// Compute phase is 100% LDS + MFMA (no VMEM), so the next input tile's
// global_load_lds DMA stays in flight underneath it (no in-order-vmcnt drain).
// grid = 512 (32 b * 16 htiles), XCD-swizzled: each XCD owns 4 whole images.
// ---------------------------------------------------------------------------
__global__ __launch_bounds__(512, 2) void conv_kernel(
    const unsigned short* __restrict__ xt, const unsigned short* __restrict__ wk,
    const int* __restrict__ task_id, float* __restrict__ out)
{
    __shared__ unsigned short ibuf[2][25344];   // 2 x 50,688 B
    __shared__ unsigned short wlds[25600];      //     51,200 B   (total 149 KiB)

    // XCD swizzle (512 = 8*64, bijective): XCD k gets blocks k*64..k*64+63
    const int blk = ((blockIdx.x & 7) << 6) | (blockIdx.x >> 3);
    const int b  = blk >> 4;
    const int ht = blk & 15;
    const int t  = task_id[b];

    const int tid  = threadIdx.x;
    const int lane = tid & 63;
    const int wave = tid >> 6;             // output row offset 0..7
    const int lane31 = lane & 31;
    const int laneh  = lane >> 5;

    floatx16 acc[2][4];
    #pragma unroll
    for (int c = 0; c < 2; ++c)
        #pragma unroll
        for (int p = 0; p < 4; ++p)
            #pragma unroll
            for (int r = 0; r < 16; ++r) acc[c][p][r] = 0.f;

    const unsigned short* wkt = wk + t * 102400;           // [25][64 co][64 ci]
    const size_t ibase0 = ((size_t)(b * 132 + ht * 8)) * 8448;

    // stage 12 input rows (padded hp = ht*8 .. +11), ci-quarter q -> ibuf[s]
    auto stage_i = [&](int s, int q) {
        const unsigned short* gsrc = xt + ibase0 + q * 2112;
        unsigned short* ldst = &ibuf[s][0];
        #pragma unroll
        for (int j = 0; j < 6; ++j) {          // 3168 uint4 = 512*6 + 96
            int i = j * 512 + tid;
            int r = i / 264;
            int rem = i - r * 264;
            gload_lds16(gsrc + (size_t)r * 8448 + rem * 8, ldst + i * 8);
        }
        if (tid < 96) {
            int i = 3072 + tid;
            int r = i / 264;
            int rem = i - r * 264;
            gload_lds16(gsrc + (size_t)r * 8448 + rem * 8, ldst + i * 8);
        }
    };
    // stage weights, ci-quarter q -> wlds[tap][cih][co][8ci]
    auto stage_w = [&](int q) {
        const unsigned short* gsrc = wkt + q * 16;
        unsigned short* ldst = &wlds[0];
        #pragma unroll
        for (int j = 0; j < 6; ++j) {          // 3200 uint4 = 512*6 + 128
            int i = j * 512 + tid;
            int tap = i >> 7;
            int rem = i & 127;
            int cih = rem >> 6;
            int co  = rem & 63;
            gload_lds16(gsrc + tap * 4096 + co * 64 + cih * 8, ldst + i * 8);
        }
        if (tid < 128) {
            int i = 3072 + tid;
            int tap = i >> 7;
            int rem = i & 127;
            int cih = rem >> 6;
            int co  = rem & 63;
            gload_lds16(gsrc + tap * 4096 + co * 64 + cih * 8, ldst + i * 8);
        }
    };

    // prologue
    stage_w(0);
    stage_i(0, 0);
    asm volatile("s_waitcnt vmcnt(0)" ::: "memory");
    __builtin_amdgcn_s_barrier();
    __builtin_amdgcn_sched_barrier(0);

    for (int q = 0; q < 4; ++q) {
        const int s = q & 1;
        if (q < 3) stage_i(s ^ 1, q + 1);      // in flight during compute below

        const unsigned short* ib = &ibuf[s][0];
        __builtin_amdgcn_s_setprio(1);
        #pragma unroll
        for (int ky = 0; ky < 5; ++ky) {
            const unsigned short* lrow = ib + (wave + ky) * 2112 + laneh * 1056;
            const unsigned short* wrow = wlds + (ky * 5) * 1024 + laneh * 512 + lane31 * 8;
            #pragma unroll
            for (int kx = 0; kx < 5; ++kx) {
                const unsigned short* ap = wrow + kx * 1024;
                bf16x8 a0 = *(const bf16x8*)(ap);
                bf16x8 a1 = *(const bf16x8*)(ap + 256);

                bf16x8 bb[4];
                #pragma unroll
                for (int p = 0; p < 4; ++p)
                    bb[p] = *(const bf16x8*)(lrow + (p * 32 + lane31 + kx) * 8);

                #pragma unroll
                for (int p = 0; p < 4; ++p) {
                    acc[0][p] = mfma16(a0, bb[p], acc[0][p]);
                    acc[1][p] = mfma16(a1, bb[p], acc[1][p]);
                }
            }
        }
        __builtin_amdgcn_s_setprio(0);

        asm volatile("s_waitcnt lgkmcnt(0)" ::: "memory");
        __builtin_amdgcn_s_barrier();          // all waves done reading wlds/ibuf[s]
        __builtin_amdgcn_sched_barrier(0);
        if (q < 3) {
            stage_w(q + 1);                    // overwrite wlds (safe after barrier)
            asm volatile("s_waitcnt vmcnt(0)" ::: "memory");  // input(q+1)+weights(q+1) landed
            __builtin_amdgcn_s_barrier();
            __builtin_amdgcn_sched_barrier(0);
        }
    }

    // Epilogue: C/D layout (32x32): col = lane&31, row = (reg&3)+8*(reg>>2)+4*(lane>>5)
    const int h = ht * 8 + wave;
    #pragma unroll
    for (int c = 0; c < 2; ++c) {
        #pragma unroll
        for (int p = 0; p < 4; ++p) {
            int w = p * 32 + lane31;
            #pragma unroll
            for (int reg = 0; reg < 16; ++reg) {
                int co = c * 32 + (reg & 3) + 8 * (reg >> 2) + 4 * laneh;
                out[((size_t)(b * 64 + co) * 128 + h) * 128 + w] = acc[c][p][reg];
            }
        }
    }
}

// ---------------------------------------------------------------------------
extern "C" void kernel_launch(void* const* d_in, const int* in_sizes, int n_in,
                              void* d_out, int out_size, void* d_ws, size_t ws_size,
                              hipStream_t stream) {
    const float* x       = (const float*)d_in[0];
    const int*   task_id = (const int*)  d_in[1];
    const float* gate_w  = (const float*)d_in[2];
    const float* gate_b  = (const float*)d_in[3];
    const float* w5      = (const float*)d_in[4];
    const float* w3      = (const float*)d_in[5];
    const float* w1      = (const float*)d_in[6];
    const float* wavg3   = (const float*)d_in[7];
    const float* wavg5   = (const float*)d_in[8];

    float* out = (float*)d_out;
    float* out_task = out + 32 * 64 * 128 * 128;   // second tuple element

    unsigned short* xt = (unsigned short*)d_ws;
    unsigned short* wk = (unsigned short*)((char*)d_ws + WK_OFFSET_BYTES);
    // requires ws_size >= 73,416,704 bytes

    pre_kernel<<<dim3(4384), dim3(256), 0, stream>>>(
        x, gate_w, gate_b, w5, w3, w1, wavg3, wavg5, task_id, xt, wk, out_task);
    conv_kernel<<<dim3(512), dim3(512), 0, stream>>>(xt, wk, task_id, out);
}

// Round 2
// 350.963 us; speedup vs baseline: 1.1793x; 1.0027x over previous
//
#include <hip/hip_runtime.h>

// Problem: B=32, CI=64, CO=64, H=128, W=128, E=5, T=10, 5x5 SAME conv (MoDE).
// d_out = y[32*64*128*128] f32 ++ task_id[32] (as float).
//
// ws layout:
//   xt : [32 b][132 hp][8 cc][132 wp][8 ci] bf16 = 71,368,704 B
//        hp = h+2 (rows 0,1,130,131 zero), wp = w+2 (borders zero)
//   wk : [10 t][25 tap][64 co][64 ci] bf16       =  2,048,000 B
// requires ws_size >= 73,416,704 bytes.
#define WK_OFFSET_BYTES 71368704ull

using bf16x8   = __attribute__((ext_vector_type(8)))  __bf16;
using floatx16 = __attribute__((ext_vector_type(16))) float;

static __device__ __forceinline__ unsigned short f2bf(float f) {
    unsigned int u = __float_as_uint(f);
    u += 0x7FFFu + ((u >> 16) & 1u);          // round-to-nearest-even (finite inputs)
    return (unsigned short)(u >> 16);
}

static __device__ __forceinline__ floatx16 mfma16(bf16x8 a, bf16x8 b, floatx16 c) {
    return __builtin_amdgcn_mfma_f32_32x32x16_bf16(a, b, c, 0, 0, 0);
}

// async global->LDS DMA, 16B per lane. LDS dest = wave-uniform base + lane*16
// (our per-lane lds pointers are consecutive, so first-lane base is correct).
static __device__ __forceinline__ void gload_lds16(const void* g, void* l) {
    __builtin_amdgcn_global_load_lds(
        (const __attribute__((address_space(1))) void*)g,
        (__attribute__((address_space(3))) void*)l, 16, 0, 0);
}

// ---------------------------------------------------------------------------
// Kernel 1 (fused): blocks 0..4223  = transform x -> xt (32 b x 132 padded rows)
//                   blocks 4224..4383 = gate softmax + per-task kernel synthesis
// ---------------------------------------------------------------------------
__global__ __launch_bounds__(256) void pre_kernel(
    const float* __restrict__ x,
    const float* __restrict__ gate_w, const float* __restrict__ gate_b,
    const float* __restrict__ w5, const float* __restrict__ w3,
    const float* __restrict__ w1, const float* __restrict__ wavg3,
    const float* __restrict__ wavg5, const int* __restrict__ task_id,
    unsigned short* __restrict__ xt, unsigned short* __restrict__ wk,
    float* __restrict__ out_task)
{
    const int blk = blockIdx.x;
    const int tid = threadIdx.x;
    __shared__ float g[5][64];

    if (blk < 4224) {
        // -------- transform: one padded row (b, hp) per block --------
        const int b  = blk / 132;
        const int hp = blk - b * 132;
        const int h  = hp - 2;
        const bool vrow = (h >= 0) && (h < 128);
        unsigned short* dst_row = xt + (size_t)blk * 8448;

        for (int i = tid; i < 1056; i += 256) {      // 8 cc * 132 wp uint4 blocks
            int cc = i / 132;
            int wp = i - cc * 132;
            unsigned int pk[4] = {0u, 0u, 0u, 0u};
            if (vrow && wp >= 2 && wp < 130) {
                const float* xp = x + (((size_t)(b * 64 + cc * 8) * 128 + h) * 128 + (wp - 2));
                #pragma unroll
                for (int j = 0; j < 4; ++j) {
                    unsigned short lo = f2bf(xp[(2 * j)     * 16384]);
                    unsigned short hi = f2bf(xp[(2 * j + 1) * 16384]);
                    pk[j] = (unsigned int)lo | ((unsigned int)hi << 16);
                }
            }
            *(uint4*)(dst_row + (size_t)i * 8) = make_uint4(pk[0], pk[1], pk[2], pk[3]);
        }
    } else {
        // -------- prep: per-task 5x5 kernel synthesis --------
        const int pb = blk - 4224;
        const int t = pb >> 4;          // 0..9
        const int chunk = pb & 15;      // 0..15

        if (tid < 64) {
            float l[5];
            float m = -1e30f;
            #pragma unroll
            for (int e = 0; e < 5; ++e) {
                l[e] = gate_w[(e * 64 + tid) * 10 + t] + gate_b[e * 64 + tid];
                m = fmaxf(m, l[e]);
            }
            float s = 0.f;
            #pragma unroll
            for (int e = 0; e < 5; ++e) { l[e] = expf(l[e] - m); s += l[e]; }
            float inv = 1.f / s;
            #pragma unroll
            for (int e = 0; e < 5; ++e) g[e][tid] = l[e] * inv;
        }
        __syncthreads();

        for (int it = 0; it < 25; ++it) {
            int idx = chunk * 6400 + it * 256 + tid;
            int ci  = idx & 63;
            int o   = (idx >> 6) & 63;
            int tap = idx >> 12;               // 0..24
            int ky = tap / 5, kx = tap - ky * 5;

            float v = g[0][o] * w5[(o * 64 + ci) * 25 + tap];
            bool in3 = (ky >= 1 && ky <= 3 && kx >= 1 && kx <= 3);
            if (in3) {
                v += g[1][o] * w3[(o * 64 + ci) * 9 + (ky - 1) * 3 + (kx - 1)];
                v += g[3][o] * wavg3[o * 64 + ci] * (1.f / 9.f);
            }
            if (ky == 2 && kx == 2) v += g[2][o] * w1[o * 64 + ci];
            v += g[4][o] * wavg5[o * 64 + ci] * (1.f / 25.f);

            wk[(t * 25 + tap) * 4096 + o * 64 + ci] = f2bf(v);
        }

        if (pb == 0 && tid < 32) out_task[tid] = (float)task_id[tid];
    }
}

// ---------------------------------------------------------------------------
// Kernel 2: MFMA conv, pipelined + ky-reuse wave decomposition.
// Block = 512 thr (8 waves), tile = 64co x (8 rows x 128 w).
// Wave = (row-group rg: 4 rows) x (w-col wc: 32 w) x 64 co -> acc[4][2].
// Per q (16-ci quarter):
//   input:  12 rows x [2 cc][132 wp][8 ci] = 50,688 B (double-buffered, DMA)
//   weights:[25 tap][2 cih][64 co][8 ci]   = 51,200 B (single-buffered, DMA)
// Inner loop: kx outer, A fragments (5 ky x 2 co-half) cached in registers;
// one B ds_read per input row feeds up to 8 MFMAs (ky-overlap reuse):
// per wave per q: 50 A + 40 B ds_read_b128 vs 200 MFMA  ->  MFMA-bound.
// grid = 512 (32 b * 16 htiles), XCD-swizzled: each XCD owns 4 whole images.
// ---------------------------------------------------------------------------
__global__ __launch_bounds__(512, 2) void conv_kernel(
    const unsigned short* __restrict__ xt, const unsigned short* __restrict__ wk,
    const int* __restrict__ task_id, float* __restrict__ out)
{
    __shared__ unsigned short ibuf[2][25344];   // 2 x 50,688 B
    __shared__ unsigned short wlds[25600];      //     51,200 B   (total 149 KiB)

    // XCD swizzle (512 = 8*64, bijective): XCD k gets blocks k*64..k*64+63
    const int blk = ((blockIdx.x & 7) << 6) | (blockIdx.x >> 3);
    const int b  = blk >> 4;
    const int ht = blk & 15;
    const int t  = task_id[b];

    const int tid  = threadIdx.x;
    const int lane = tid & 63;
    const int wave = tid >> 6;
    const int rg = wave >> 2;              // row group 0..1 (4 output rows each)
    const int wc = wave & 3;               // w column 0..3 (32 outputs each)
    const int lane31 = lane & 31;
    const int laneh  = lane >> 5;

    floatx16 acc[4][2];                    // [out row o][co half]
    #pragma unroll
    for (int o = 0; o < 4; ++o)
        #pragma unroll
        for (int c = 0; c < 2; ++c)
            #pragma unroll
            for (int r = 0; r < 16; ++r) acc[o][c][r] = 0.f;

    const unsigned short* wkt = wk + t * 102400;           // [25][64 co][64 ci]
    const size_t ibase0 = ((size_t)(b * 132 + ht * 8)) * 8448;

    // stage 12 input rows (padded hp = ht*8 .. +11), ci-quarter q -> ibuf[s]
    auto stage_i = [&](int s, int q) {
        const unsigned short* gsrc = xt + ibase0 + q * 2112;
        unsigned short* ldst = &ibuf[s][0];
        #pragma unroll
        for (int j = 0; j < 6; ++j) {          // 3168 uint4 = 512*6 + 96
            int i = j * 512 + tid;
            int r = i / 264;
            int rem = i - r * 264;
            gload_lds16(gsrc + (size_t)r * 8448 + rem * 8, ldst + i * 8);
        }
        if (tid < 96) {
            int i = 3072 + tid;
            int r = i / 264;
            int rem = i - r * 264;
            gload_lds16(gsrc + (size_t)r * 8448 + rem * 8, ldst + i * 8);
        }
    };
    // stage weights, ci-quarter q -> wlds[tap][cih][co][8ci]
    auto stage_w = [&](int q) {
        const unsigned short* gsrc = wkt + q * 16;
        unsigned short* ldst = &wlds[0];
        #pragma unroll
        for (int j = 0; j < 6; ++j) {          // 3200 uint4 = 512*6 + 128
            int i = j * 512 + tid;
            int tap = i >> 7;
            int rem = i & 127;
            int cih = rem >> 6;
            int co  = rem & 63;
            gload_lds16(gsrc + tap * 4096 + co * 64 + cih * 8, ldst + i * 8);
        }
        if (tid < 128) {
            int i = 3072 + tid;
            int tap = i >> 7;
            int rem = i & 127;
            int cih = rem >> 6;
            int co  = rem & 63;
            gload_lds16(gsrc + tap * 4096 + co * 64 + cih * 8, ldst + i * 8);
        }
    };

    // prologue
    stage_w(0);
    stage_i(0, 0);
    asm volatile("s_waitcnt vmcnt(0)" ::: "memory");
    __builtin_amdgcn_s_barrier();
    __builtin_amdgcn_sched_barrier(0);

    for (int q = 0; q < 4; ++q) {
        const int s = q & 1;
        if (q < 3) stage_i(s ^ 1, q + 1);      // in flight during compute below

        const unsigned short* ib = &ibuf[s][0];
        __builtin_amdgcn_s_setprio(1);
        #pragma unroll
        for (int kx = 0; kx < 5; ++kx) {
            // cache A fragments for this kx: 5 ky x 2 co-halves (40 VGPR)
            bf16x8 aF[5][2];
            #pragma unroll
            for (int ky = 0; ky < 5; ++ky) {
                const unsigned short* ap =
                    wlds + (ky * 5 + kx) * 1024 + laneh * 512 + lane31 * 8;
                aF[ky][0] = *(const bf16x8*)(ap);
                aF[ky][1] = *(const bf16x8*)(ap + 256);
            }
            // one B read per staged input row feeds up to 8 MFMAs
            #pragma unroll
            for (int hr = 0; hr < 8; ++hr) {
                const unsigned short* bp =
                    ib + (rg * 4 + hr) * 2112 + laneh * 1056
                       + (wc * 32 + lane31 + kx) * 8;
                bf16x8 bb = *(const bf16x8*)bp;
                #pragma unroll
                for (int ky = 0; ky < 5; ++ky) {
                    const int o = hr - ky;     // compile-time after unroll
                    if (o >= 0 && o < 4) {
                        acc[o][0] = mfma16(aF[ky][0], bb, acc[o][0]);
                        acc[o][1] = mfma16(aF[ky][1], bb, acc[o][1]);
                    }
                }
            }
        }
        __builtin_amdgcn_s_setprio(0);

        asm volatile("s_waitcnt lgkmcnt(0)" ::: "memory");
        __builtin_amdgcn_s_barrier();          // all waves done reading wlds/ibuf[s]
        __builtin_amdgcn_sched_barrier(0);
        if (q < 3) {
            stage_w(q + 1);                    // overwrite wlds (safe after barrier)
            asm volatile("s_waitcnt vmcnt(0)" ::: "memory");  // input+weights landed
            __builtin_amdgcn_s_barrier();
            __builtin_amdgcn_sched_barrier(0);
        }
    }

    // Epilogue: C/D layout (32x32): col(w) = lane&31, row(co) = (reg&3)+8*(reg>>2)+4*(lane>>5)
    #pragma unroll
    for (int o = 0; o < 4; ++o) {
        const int h = ht * 8 + rg * 4 + o;
        #pragma unroll
        for (int c = 0; c < 2; ++c) {
            const int w = wc * 32 + lane31;
            #pragma unroll
            for (int reg = 0; reg < 16; ++reg) {
                int co = c * 32 + (reg & 3) + 8 * (reg >> 2) + 4 * laneh;
                out[((size_t)(b * 64 + co) * 128 + h) * 128 + w] = acc[o][c][reg];
            }
        }
    }
}

// ---------------------------------------------------------------------------
extern "C" void kernel_launch(void* const* d_in, const int* in_sizes, int n_in,
                              void* d_out, int out_size, void* d_ws, size_t ws_size,
                              hipStream_t stream) {
    const float* x       = (const float*)d_in[0];
    const int*   task_id = (const int*)  d_in[1];
    const float* gate_w  = (const float*)d_in[2];
    const float* gate_b  = (const float*)d_in[3];
    const float* w5      = (const float*)d_in[4];
    const float* w3      = (const float*)d_in[5];
    const float* w1      = (const float*)d_in[6];
    const float* wavg3   = (const float*)d_in[7];
    const float* wavg5   = (const float*)d_in[8];

    float* out = (float*)d_out;
    float* out_task = out + 32 * 64 * 128 * 128;   // second tuple element

    unsigned short* xt = (unsigned short*)d_ws;
    unsigned short* wk = (unsigned short*)((char*)d_ws + WK_OFFSET_BYTES);
    // requires ws_size >= 73,416,704 bytes

    pre_kernel<<<dim3(4384), dim3(256), 0, stream>>>(
        x, gate_w, gate_b, w5, w3, w1, wavg3, wavg5, task_id, xt, wk, out_task);
    conv_kernel<<<dim3(512), dim3(512), 0, stream>>>(xt, wk, task_id, out);
}